// Round 4
// baseline (300.969 us; speedup 1.0000x reference)
//
#include <hip/hip_runtime.h>
#include <math.h>

#define TKK 512
#define TQQ 128
#define BB  8
#define EE  128
#define DD  82
#define IND 41
#define HH  128
#define G3  384
#define NL  50
#define OD  40

typedef __attribute__((ext_vector_type(8))) short short8v;
typedef __attribute__((ext_vector_type(4))) float f32x4;
#define MFMA16(a, b, c) __builtin_amdgcn_mfma_f32_16x16x32_bf16(a, b, c, 0, 0, 0)

__device__ __forceinline__ short f2bf(float f) {
  unsigned u = __float_as_uint(f);
  unsigned r = (u + 0x7fffu + ((u >> 16) & 1u)) >> 16;  // RNE
  return (short)r;
}

// ---------------- Kernel A: time embeddings + K/Q projections ----------------
__global__ void embed_project(const float* __restrict__ time_steps,
                              const float* __restrict__ query,
                              const float* __restrict__ e1_wp, const float* __restrict__ e1_bp,
                              const float* __restrict__ e1_wl, const float* __restrict__ e1_bl,
                              const float* __restrict__ e2_wp, const float* __restrict__ e2_bp,
                              const float* __restrict__ e2_wl, const float* __restrict__ e2_bl,
                              const float* __restrict__ Wk, const float* __restrict__ bk,
                              const float* __restrict__ Wq, const float* __restrict__ bq,
                              float* __restrict__ kproj, float* __restrict__ qproj) {
  __shared__ float emb[EE];
  int row = blockIdx.x;
  int e = threadIdx.x;
  float t; const float *wp, *bp, *wl, *bl, *W, *bias; float* out;
  if (row < BB * TKK) {
    t = time_steps[row];
    wp = e1_wp; bp = e1_bp; wl = e1_wl; bl = e1_bl; W = Wk; bias = bk;
    out = kproj + (size_t)row * EE;
  } else {
    int qi = row - BB * TKK;
    t = query[qi];
    wp = e2_wp; bp = e2_bp; wl = e2_wl; bl = e2_bl; W = Wq; bias = bq;
    out = qproj + (size_t)qi * EE;
  }
  emb[e] = (e == 0) ? (t * wl[0] + bl[0]) : sinf(t * wp[e - 1] + bp[e - 1]);
  __syncthreads();
  const float4* wr = (const float4*)(W + (size_t)e * EE);
  const float4* ev = (const float4*)emb;
  float acc = bias[e];
#pragma unroll 8
  for (int i = 0; i < EE / 4; i++) {
    float4 a = wr[i]; float4 c = ev[i];
    acc += a.x * c.x + a.y * c.y + a.z * c.z + a.w * c.w;
  }
  out[e] = acc;
}

// ---------------- Kernel B: masked-softmax attention + Wo projection ----------------
__global__ void attention(const float* __restrict__ x,
                          const float* __restrict__ kproj,
                          const float* __restrict__ qproj,
                          const float* __restrict__ Wo, const float* __restrict__ bo,
                          float* __restrict__ xs) {
  __shared__ float qv[EE];
  __shared__ float w[TKK];
  __shared__ float red[8];
  __shared__ float part[2 * DD];
  __shared__ float numb[DD];
  __shared__ float attb[DD];
  int b = blockIdx.x >> 7, q = blockIdx.x & 127;
  int tid = threadIdx.x;  // 256
  if (tid < EE) qv[tid] = qproj[(size_t)q * EE + tid];
  __syncthreads();
  float lmax = -1e30f;
  for (int r = 0; r < 2; r++) {
    int k = tid + r * 256;
    const float4* kr = (const float4*)(kproj + (size_t)(b * TKK + k) * EE);
    const float4* qv4 = (const float4*)qv;
    float acc = 0.f;
#pragma unroll 8
    for (int i = 0; i < EE / 4; i++) {
      float4 a = kr[i]; float4 c = qv4[i];
      acc += a.x * c.x + a.y * c.y + a.z * c.z + a.w * c.w;
    }
    acc *= 0.08838834764831845f;  // 1/sqrt(128)
    w[k] = acc;
    lmax = fmaxf(lmax, acc);
  }
  for (int off = 32; off; off >>= 1) lmax = fmaxf(lmax, __shfl_xor(lmax, off, 64));
  if ((tid & 63) == 0) red[tid >> 6] = lmax;
  __syncthreads();
  if (tid == 0) {
    float m = red[0];
    for (int i = 1; i < 4; i++) m = fmaxf(m, red[i]);
    red[0] = m;
  }
  __syncthreads();
  float m = red[0];
  for (int r = 0; r < 2; r++) { int k = tid + r * 256; w[k] = __expf(w[k] - m); }
  __syncthreads();
  if (tid < 2 * DD) {
    int c = tid / DD, d = tid - c * DD;
    const float* xp = x + (size_t)(b * TKK + c * 256) * DD + d;
    float acc = 0.f;
#pragma unroll 4
    for (int k = 0; k < 256; k++) acc += w[c * 256 + k] * xp[(size_t)k * DD];
    part[tid] = acc;
  }
  __syncthreads();
  if (tid < DD) numb[tid] = part[tid] + part[DD + tid];
  __syncthreads();
  if (tid < DD) {
    int j = tid % IND;
    attb[tid] = numb[tid] / numb[IND + j];
  }
  __syncthreads();
  if (tid < HH) {
    const float* wo = Wo + (size_t)tid * DD;
    float acc = bo[tid];
#pragma unroll 2
    for (int d = 0; d < DD; d++) acc += wo[d] * attb[d];
    xs[((size_t)q * BB + b) * HH + tid] = acc;  // xs layout [TQ][B][H]
  }
}

// ---------------- Kernel C: precompute input gates gi ----------------
__global__ void gi_precompute(const float* __restrict__ xs,
                              const float* __restrict__ gwi_f, const float* __restrict__ gbi_f,
                              const float* __restrict__ gwi_b, const float* __restrict__ gbi_b,
                              float* __restrict__ gi) {
  __shared__ float xr[BB][EE];
  int dir = blockIdx.x >> 7, t = blockIdx.x & 127;
  const float* Wi = dir ? gwi_b : gwi_f;
  const float* bi = dir ? gbi_b : gbi_f;
  int tid = threadIdx.x;  // 384
  for (int idx = tid; idx < BB * EE; idx += G3)
    xr[idx >> 7][idx & 127] = xs[(size_t)t * BB * EE + idx];
  __syncthreads();
  const float* wr = Wi + (size_t)tid * EE;
  float bias = bi[tid];
  float acc[BB];
#pragma unroll
  for (int b = 0; b < BB; b++) acc[b] = bias;
  for (int i = 0; i < EE; i++) {
    float wv = wr[i];
#pragma unroll
    for (int b = 0; b < BB; b++) acc[b] += wv * xr[b][i];
  }
  size_t base = ((size_t)(dir * TQQ + t) * BB) * G3 + tid;
#pragma unroll
  for (int b = 0; b < BB; b++) gi[base + (size_t)b * G3] = acc[b];
}

// ---------------- Kernel D: sequential GRU via MFMA, software-pipelined ----------------
// 2 blocks (one per direction), 512 threads = 8 waves.
// gi prefetched 1 step ahead into registers; hcat stores buffered in regs,
// flushed every 8 steps; one barrier per step; h double-buffered bf16 in LDS.
__global__ __launch_bounds__(512, 1) void gru_seq(const float* __restrict__ gi,
                                                  const float* __restrict__ gwh_f,
                                                  const float* __restrict__ gbh_f,
                                                  const float* __restrict__ gwh_b,
                                                  const float* __restrict__ gbh_b,
                                                  float* __restrict__ hcat) {
  __shared__ short hb[2][16][HH];  // bf16, rows 8..15 stay zero (MFMA M=16 pad)
  int dir = blockIdx.x;
  const float* Wh = dir ? gwh_b : gwh_f;
  const float* bh = dir ? gbh_b : gbh_f;
  int tid = threadIdx.x;
  int w = tid >> 6, l = tid & 63;
  int lhi = l >> 4, llo = l & 15;
  int o = 16 * w + llo;            // gate/output column this thread covers
  bool valid = (lhi < 2);          // batch rows b = 4*lhi+j < 8

  for (int i = tid; i < 2 * 16 * HH / 2; i += 512) ((int*)hb)[i] = 0;

  // B fragments: B[k][n] = Wh[n][k], n = gate col o, lane holds k=kk*32+8*lhi+[0..8)
  short8v Bf[3][4];
#pragma unroll
  for (int g = 0; g < 3; g++) {
    const float* wr = Wh + (size_t)(g * HH + o) * EE;
#pragma unroll
    for (int kk = 0; kk < 4; kk++) {
      int k0 = kk * 32 + lhi * 8;
      short8v v;
#pragma unroll
      for (int i = 0; i < 8; i++) v[i] = f2bf(wr[k0 + i]);
      Bf[g][kk] = v;
    }
  }
  float bhr = bh[o], bhz = bh[HH + o], bhn = bh[2 * HH + o];
  float hprev[4] = {0.f, 0.f, 0.f, 0.f};
  int swzA = (llo & 7) << 4;
  float hst[8][4];  // [si][j] store buffer, all indices compile-time

  // gi double-buffer registers, [gate*4 + j]
  float ga[12], gb[12];
  const size_t dbase = (size_t)dir * TQQ * BB * G3;

  auto gi_load = [&](int step, float (&dst)[12]) {
    int tt = dir ? (TQQ - 1 - step) : step;
    const float* gp0 = gi + dbase + (size_t)tt * (BB * G3) + (size_t)(4 * lhi) * G3 + o;
#pragma unroll
    for (int j = 0; j < 4; j++) {
      const float* gp = gp0 + (size_t)j * G3;
      dst[j] = gp[0]; dst[4 + j] = gp[HH]; dst[8 + j] = gp[2 * HH];
    }
  };
  if (valid) gi_load(0, ga);
  __syncthreads();

  auto body = [&](int step, float (&gc)[12], float (&gn)[12], float (&hs)[4]) {
    int cur = step & 1;
    // A fragments: A[m][k] = h[m][k], m = llo, k = kk*32 + 8*lhi + [0..8)
    const char* hrow = (const char*)&hb[cur][llo][0];
    short8v A0 = *(const short8v*)(hrow + ((0 * 64 + lhi * 16) ^ swzA));
    short8v A1 = *(const short8v*)(hrow + ((1 * 64 + lhi * 16) ^ swzA));
    short8v A2 = *(const short8v*)(hrow + ((2 * 64 + lhi * 16) ^ swzA));
    short8v A3 = *(const short8v*)(hrow + ((3 * 64 + lhi * 16) ^ swzA));
    // prefetch next step's gi (consumed next iteration — a full step of cover)
    if (valid) gi_load(step < TQQ - 1 ? step + 1 : step, gn);
    f32x4 accR = {0.f, 0.f, 0.f, 0.f}, accZ = {0.f, 0.f, 0.f, 0.f}, accN = {0.f, 0.f, 0.f, 0.f};
    accR = MFMA16(A0, Bf[0][0], accR); accZ = MFMA16(A0, Bf[1][0], accZ); accN = MFMA16(A0, Bf[2][0], accN);
    accR = MFMA16(A1, Bf[0][1], accR); accZ = MFMA16(A1, Bf[1][1], accZ); accN = MFMA16(A1, Bf[2][1], accN);
    accR = MFMA16(A2, Bf[0][2], accR); accZ = MFMA16(A2, Bf[1][2], accZ); accN = MFMA16(A2, Bf[2][2], accN);
    accR = MFMA16(A3, Bf[0][3], accR); accZ = MFMA16(A3, Bf[1][3], accZ); accN = MFMA16(A3, Bf[2][3], accN);
    if (valid) {
#pragma unroll
      for (int j = 0; j < 4; j++) {
        int m = 4 * lhi + j;  // batch row
        float rp = gc[j] + bhr + accR[j];
        float zp = gc[4 + j] + bhz + accZ[j];
        float hn = accN[j] + bhn;
        float r = 1.f / (1.f + __expf(-rp));
        float z = 1.f / (1.f + __expf(-zp));
        float a = gc[8 + j] + r * hn;
        float e = __expf(2.f * a);
        float n = 1.f - 2.f / (1.f + e);  // tanh(a), saturation-safe
        float hnew = n + z * (hprev[j] - n);
        hprev[j] = hnew;
        hs[j] = hnew;
        *(short*)((char*)&hb[cur ^ 1][m][0] + ((o * 2) ^ ((m & 7) << 4))) = f2bf(hnew);
      }
    }
    __syncthreads();
  };

  for (int so = 0; so < TQQ / 8; so++) {
    body(so * 8 + 0, ga, gb, hst[0]);
    body(so * 8 + 1, gb, ga, hst[1]);
    body(so * 8 + 2, ga, gb, hst[2]);
    body(so * 8 + 3, gb, ga, hst[3]);
    body(so * 8 + 4, ga, gb, hst[4]);
    body(so * 8 + 5, gb, ga, hst[5]);
    body(so * 8 + 6, ga, gb, hst[6]);
    body(so * 8 + 7, gb, ga, hst[7]);
    if (valid) {
#pragma unroll
      for (int si = 0; si < 8; si++) {
        int step = so * 8 + si;
        int t = dir ? (TQQ - 1 - step) : step;
#pragma unroll
        for (int j = 0; j < 4; j++) {
          int m = 4 * lhi + j;
          hcat[((size_t)m * TQQ + t) * (2 * HH) + dir * HH + o] = hst[si][j];
        }
      }
    }
  }
}

// ---------------- Kernel E: final MLP ----------------
__global__ void mlp_out(const float* __restrict__ hcat,
                        const float* __restrict__ W1, const float* __restrict__ b1,
                        const float* __restrict__ W2, const float* __restrict__ b2,
                        float* __restrict__ out) {
  __shared__ float hrow[2 * HH];
  __shared__ float ybuf[NL];
  int bt = blockIdx.x;
  int tid = threadIdx.x;  // 64
  for (int idx = tid; idx < 2 * HH; idx += 64) hrow[idx] = hcat[(size_t)bt * 2 * HH + idx];
  __syncthreads();
  if (tid < NL) {
    const float* wr = W1 + (size_t)tid * 2 * HH;
    float acc = b1[tid];
#pragma unroll 4
    for (int i = 0; i < 2 * HH; i++) acc += wr[i] * hrow[i];
    ybuf[tid] = fmaxf(acc, 0.f);
  }
  __syncthreads();
  if (tid < OD) {
    const float* wr = W2 + (size_t)tid * NL;
    float acc = b2[tid];
#pragma unroll 2
    for (int j = 0; j < NL; j++) acc += wr[j] * ybuf[j];
    out[(size_t)bt * OD + tid] = acc;
  }
}

extern "C" void kernel_launch(void* const* d_in, const int* in_sizes, int n_in,
                              void* d_out, int out_size, void* d_ws, size_t ws_size,
                              hipStream_t stream) {
  const float* x          = (const float*)d_in[0];
  const float* time_steps = (const float*)d_in[1];
  const float* query      = (const float*)d_in[2];
  const float* e1_wp = (const float*)d_in[3];
  const float* e1_bp = (const float*)d_in[4];
  const float* e1_wl = (const float*)d_in[5];
  const float* e1_bl = (const float*)d_in[6];
  const float* e2_wp = (const float*)d_in[7];
  const float* e2_bp = (const float*)d_in[8];
  const float* e2_wl = (const float*)d_in[9];
  const float* e2_bl = (const float*)d_in[10];
  const float* Wq = (const float*)d_in[11];
  const float* bq = (const float*)d_in[12];
  const float* Wk = (const float*)d_in[13];
  const float* bk = (const float*)d_in[14];
  const float* Wo = (const float*)d_in[15];
  const float* bo = (const float*)d_in[16];
  const float* gwi_f = (const float*)d_in[17];
  const float* gwh_f = (const float*)d_in[18];
  const float* gbi_f = (const float*)d_in[19];
  const float* gbh_f = (const float*)d_in[20];
  const float* gwi_b = (const float*)d_in[21];
  const float* gwh_b = (const float*)d_in[22];
  const float* gbi_b = (const float*)d_in[23];
  const float* gbh_b = (const float*)d_in[24];
  const float* W1 = (const float*)d_in[25];
  const float* b1 = (const float*)d_in[26];
  const float* W2 = (const float*)d_in[27];
  const float* b2 = (const float*)d_in[28];

  float* ws    = (float*)d_ws;
  float* kproj = ws;                       // 4096*128
  float* qproj = kproj + 4096 * 128;       // 128*128
  float* xs    = qproj + 128 * 128;        // 128*8*128
  float* gi    = xs + 128 * 8 * 128;       // 2*128*8*384
  float* hcat  = gi + 2 * 128 * 8 * 384;   // 8*128*256

  embed_project<<<4224, 128, 0, stream>>>(time_steps, query,
                                          e1_wp, e1_bp, e1_wl, e1_bl,
                                          e2_wp, e2_bp, e2_wl, e2_bl,
                                          Wk, bk, Wq, bq, kproj, qproj);
  attention<<<1024, 256, 0, stream>>>(x, kproj, qproj, Wo, bo, xs);
  gi_precompute<<<256, 384, 0, stream>>>(xs, gwi_f, gbi_f, gwi_b, gbi_b, gi);
  gru_seq<<<2, 512, 0, stream>>>(gi, gwh_f, gbh_f, gwh_b, gbh_b, hcat);
  mlp_out<<<1024, 64, 0, stream>>>(hcat, W1, b1, W2, b2, (float*)d_out);
}

// Round 5
// 300.673 us; speedup vs baseline: 1.0010x; 1.0010x over previous
//
#include <hip/hip_runtime.h>
#include <math.h>

#define TKK 512
#define TQQ 128
#define BB  8
#define EE  128
#define DD  82
#define IND 41
#define HH  128
#define G3  384
#define NL  50
#define OD  40

typedef __attribute__((ext_vector_type(8))) short short8v;
typedef __attribute__((ext_vector_type(4))) float f32x4;
#define MFMA16(a, b, c) __builtin_amdgcn_mfma_f32_16x16x32_bf16(a, b, c, 0, 0, 0)

__device__ __forceinline__ short f2bf(float f) {
  unsigned u = __float_as_uint(f);
  unsigned r = (u + 0x7fffu + ((u >> 16) & 1u)) >> 16;  // RNE
  return (short)r;
}

// ---------------- Kernel A: time embeddings + K/Q projections ----------------
__global__ void embed_project(const float* __restrict__ time_steps,
                              const float* __restrict__ query,
                              const float* __restrict__ e1_wp, const float* __restrict__ e1_bp,
                              const float* __restrict__ e1_wl, const float* __restrict__ e1_bl,
                              const float* __restrict__ e2_wp, const float* __restrict__ e2_bp,
                              const float* __restrict__ e2_wl, const float* __restrict__ e2_bl,
                              const float* __restrict__ Wk, const float* __restrict__ bk,
                              const float* __restrict__ Wq, const float* __restrict__ bq,
                              float* __restrict__ kproj, float* __restrict__ qproj) {
  __shared__ float emb[EE];
  int row = blockIdx.x;
  int e = threadIdx.x;
  float t; const float *wp, *bp, *wl, *bl, *W, *bias; float* out;
  if (row < BB * TKK) {
    t = time_steps[row];
    wp = e1_wp; bp = e1_bp; wl = e1_wl; bl = e1_bl; W = Wk; bias = bk;
    out = kproj + (size_t)row * EE;
  } else {
    int qi = row - BB * TKK;
    t = query[qi];
    wp = e2_wp; bp = e2_bp; wl = e2_wl; bl = e2_bl; W = Wq; bias = bq;
    out = qproj + (size_t)qi * EE;
  }
  emb[e] = (e == 0) ? (t * wl[0] + bl[0]) : sinf(t * wp[e - 1] + bp[e - 1]);
  __syncthreads();
  const float4* wr = (const float4*)(W + (size_t)e * EE);
  const float4* ev = (const float4*)emb;
  float acc = bias[e];
#pragma unroll 8
  for (int i = 0; i < EE / 4; i++) {
    float4 a = wr[i]; float4 c = ev[i];
    acc += a.x * c.x + a.y * c.y + a.z * c.z + a.w * c.w;
  }
  out[e] = acc;
}

// ---------------- Kernel B: masked-softmax attention + Wo projection ----------------
__global__ void attention(const float* __restrict__ x,
                          const float* __restrict__ kproj,
                          const float* __restrict__ qproj,
                          const float* __restrict__ Wo, const float* __restrict__ bo,
                          float* __restrict__ xs) {
  __shared__ float qv[EE];
  __shared__ float w[TKK];
  __shared__ float red[8];
  __shared__ float part[2 * DD];
  __shared__ float numb[DD];
  __shared__ float attb[DD];
  int b = blockIdx.x >> 7, q = blockIdx.x & 127;
  int tid = threadIdx.x;  // 256
  if (tid < EE) qv[tid] = qproj[(size_t)q * EE + tid];
  __syncthreads();
  float lmax = -1e30f;
  for (int r = 0; r < 2; r++) {
    int k = tid + r * 256;
    const float4* kr = (const float4*)(kproj + (size_t)(b * TKK + k) * EE);
    const float4* qv4 = (const float4*)qv;
    float acc = 0.f;
#pragma unroll 8
    for (int i = 0; i < EE / 4; i++) {
      float4 a = kr[i]; float4 c = qv4[i];
      acc += a.x * c.x + a.y * c.y + a.z * c.z + a.w * c.w;
    }
    acc *= 0.08838834764831845f;  // 1/sqrt(128)
    w[k] = acc;
    lmax = fmaxf(lmax, acc);
  }
  for (int off = 32; off; off >>= 1) lmax = fmaxf(lmax, __shfl_xor(lmax, off, 64));
  if ((tid & 63) == 0) red[tid >> 6] = lmax;
  __syncthreads();
  if (tid == 0) {
    float m = red[0];
    for (int i = 1; i < 4; i++) m = fmaxf(m, red[i]);
    red[0] = m;
  }
  __syncthreads();
  float m = red[0];
  for (int r = 0; r < 2; r++) { int k = tid + r * 256; w[k] = __expf(w[k] - m); }
  __syncthreads();
  if (tid < 2 * DD) {
    int c = tid / DD, d = tid - c * DD;
    const float* xp = x + (size_t)(b * TKK + c * 256) * DD + d;
    float acc = 0.f;
#pragma unroll 4
    for (int k = 0; k < 256; k++) acc += w[c * 256 + k] * xp[(size_t)k * DD];
    part[tid] = acc;
  }
  __syncthreads();
  if (tid < DD) numb[tid] = part[tid] + part[DD + tid];
  __syncthreads();
  if (tid < DD) {
    int j = tid % IND;
    attb[tid] = numb[tid] / numb[IND + j];
  }
  __syncthreads();
  if (tid < HH) {
    const float* wo = Wo + (size_t)tid * DD;
    float acc = bo[tid];
#pragma unroll 2
    for (int d = 0; d < DD; d++) acc += wo[d] * attb[d];
    xs[((size_t)q * BB + b) * HH + tid] = acc;  // xs layout [TQ][B][H]
  }
}

// ---------------- Kernel C: precompute input gates gi ----------------
__global__ void gi_precompute(const float* __restrict__ xs,
                              const float* __restrict__ gwi_f, const float* __restrict__ gbi_f,
                              const float* __restrict__ gwi_b, const float* __restrict__ gbi_b,
                              float* __restrict__ gi) {
  __shared__ float xr[BB][EE];
  int dir = blockIdx.x >> 7, t = blockIdx.x & 127;
  const float* Wi = dir ? gwi_b : gwi_f;
  const float* bi = dir ? gbi_b : gbi_f;
  int tid = threadIdx.x;  // 384
  for (int idx = tid; idx < BB * EE; idx += G3)
    xr[idx >> 7][idx & 127] = xs[(size_t)t * BB * EE + idx];
  __syncthreads();
  const float* wr = Wi + (size_t)tid * EE;
  float bias = bi[tid];
  float acc[BB];
#pragma unroll
  for (int b = 0; b < BB; b++) acc[b] = bias;
  for (int i = 0; i < EE; i++) {
    float wv = wr[i];
#pragma unroll
    for (int b = 0; b < BB; b++) acc[b] += wv * xr[b][i];
  }
  size_t base = ((size_t)(dir * TQQ + t) * BB) * G3 + tid;
#pragma unroll
  for (int b = 0; b < BB; b++) gi[base + (size_t)b * G3] = acc[b];
}

// ---------------- Kernel D: sequential GRU via MFMA, raw-barrier pipeline ----------------
// 2 blocks (one per direction), 512 threads = 8 waves.
// Key fix vs r3/r4: in-loop sync is {lgkmcnt(0); raw s_barrier} — NO vmcnt
// drain, so gi prefetch loads (2 steps ahead, 4 rotating reg buffers) and
// hcat stores stay in flight across barriers; the compiler's per-use
// vmcnt(N) waits handle consumption.
__global__ __launch_bounds__(512, 1) void gru_seq(const float* __restrict__ gi,
                                                  const float* __restrict__ gwh_f,
                                                  const float* __restrict__ gbh_f,
                                                  const float* __restrict__ gwh_b,
                                                  const float* __restrict__ gbh_b,
                                                  float* __restrict__ hcat) {
  __shared__ short hb[2][16][HH];  // bf16, rows 8..15 stay zero (MFMA M=16 pad)
  int dir = blockIdx.x;
  const float* Wh = dir ? gwh_b : gwh_f;
  const float* bh = dir ? gbh_b : gbh_f;
  int tid = threadIdx.x;
  int w = tid >> 6, l = tid & 63;
  int lhi = l >> 4, llo = l & 15;
  int o = 16 * w + llo;            // gate/output column this thread covers
  bool valid = (lhi < 2);          // batch rows b = 4*lhi+j < 8

  for (int i = tid; i < 2 * 16 * HH / 2; i += 512) ((int*)hb)[i] = 0;

  // B fragments: B[k][n] = Wh[n][k], n = gate col o, lane holds k=kk*32+8*lhi+[0..8)
  short8v Bf[3][4];
#pragma unroll
  for (int g = 0; g < 3; g++) {
    const float* wr = Wh + (size_t)(g * HH + o) * EE;
#pragma unroll
    for (int kk = 0; kk < 4; kk++) {
      int k0 = kk * 32 + lhi * 8;
      short8v v;
#pragma unroll
      for (int i = 0; i < 8; i++) v[i] = f2bf(wr[k0 + i]);
      Bf[g][kk] = v;
    }
  }
  float bhr = bh[o], bhz = bh[HH + o], bhn = bh[2 * HH + o];
  float hprev[4] = {0.f, 0.f, 0.f, 0.f};
  int swzA = (llo & 7) << 4;

  // gi rotating buffers (static indices only), [gate*4 + j]
  float g0[12], g1[12], g2[12], g3[12];
  const size_t dbase = (size_t)dir * TQQ * BB * G3;

  auto gi_load = [&](int step, float (&dst)[12]) {
    int tt = dir ? (TQQ - 1 - step) : step;
    const float* gp0 = gi + dbase + (size_t)tt * (BB * G3) + (size_t)(4 * lhi) * G3 + o;
#pragma unroll
    for (int j = 0; j < 4; j++) {
      const float* gp = gp0 + (size_t)j * G3;
      dst[j] = gp[0]; dst[4 + j] = gp[HH]; dst[8 + j] = gp[2 * HH];
    }
  };
  __syncthreads();           // one full-drain barrier at init is fine
  if (valid) { gi_load(0, g0); gi_load(1, g1); }

  auto body = [&](int step, float (&gc)[12], float (&gn)[12]) {
    int cur = step & 1;
    // A fragments: A[m][k] = h[m][k], m = llo, k = kk*32 + 8*lhi + [0..8)
    const char* hrow = (const char*)&hb[cur][llo][0];
    short8v A0 = *(const short8v*)(hrow + ((0 * 64 + lhi * 16) ^ swzA));
    short8v A1 = *(const short8v*)(hrow + ((1 * 64 + lhi * 16) ^ swzA));
    short8v A2 = *(const short8v*)(hrow + ((2 * 64 + lhi * 16) ^ swzA));
    short8v A3 = *(const short8v*)(hrow + ((3 * 64 + lhi * 16) ^ swzA));
    // prefetch gi two steps ahead (in flight across 2 barriers)
    if (valid) { int ls = step + 2; gi_load(ls > TQQ - 1 ? TQQ - 1 : ls, gn); }
    // split chains: depth 2 per gate + one vector add
    f32x4 z4 = {0.f, 0.f, 0.f, 0.f};
    f32x4 aR0 = z4, aR1 = z4, aZ0 = z4, aZ1 = z4, aN0 = z4, aN1 = z4;
    aR0 = MFMA16(A0, Bf[0][0], aR0); aZ0 = MFMA16(A0, Bf[1][0], aZ0); aN0 = MFMA16(A0, Bf[2][0], aN0);
    aR1 = MFMA16(A1, Bf[0][1], aR1); aZ1 = MFMA16(A1, Bf[1][1], aZ1); aN1 = MFMA16(A1, Bf[2][1], aN1);
    aR0 = MFMA16(A2, Bf[0][2], aR0); aZ0 = MFMA16(A2, Bf[1][2], aZ0); aN0 = MFMA16(A2, Bf[2][2], aN0);
    aR1 = MFMA16(A3, Bf[0][3], aR1); aZ1 = MFMA16(A3, Bf[1][3], aZ1); aN1 = MFMA16(A3, Bf[2][3], aN1);
    if (valid) {
      int t = dir ? (TQQ - 1 - step) : step;
#pragma unroll
      for (int j = 0; j < 4; j++) {
        int m = 4 * lhi + j;  // batch row
        float rp = gc[j] + bhr + (aR0[j] + aR1[j]);
        float zp = gc[4 + j] + bhz + (aZ0[j] + aZ1[j]);
        float hn = (aN0[j] + aN1[j]) + bhn;
        float r = 1.f / (1.f + __expf(-rp));
        float z = 1.f / (1.f + __expf(-zp));
        float a = gc[8 + j] + r * hn;
        float e = __expf(2.f * a);
        float n = 1.f - 2.f / (1.f + e);  // tanh(a), saturation-safe
        float hnew = n + z * (hprev[j] - n);
        hprev[j] = hnew;
        *(short*)((char*)&hb[cur ^ 1][m][0] + ((o * 2) ^ ((m & 7) << 4))) = f2bf(hnew);
        hcat[((size_t)m * TQQ + t) * (2 * HH) + dir * HH + o] = hnew;
      }
    }
    // LDS-only sync: drain own ds ops, raw barrier, no vmcnt(0) drain
    asm volatile("s_waitcnt lgkmcnt(0)" ::: "memory");
    __builtin_amdgcn_s_barrier();
    __builtin_amdgcn_sched_barrier(0);
  };

  for (int so = 0; so < TQQ / 4; so++) {
    body(so * 4 + 0, g0, g2);
    body(so * 4 + 1, g1, g3);
    body(so * 4 + 2, g2, g0);
    body(so * 4 + 3, g3, g1);
  }
}

// ---------------- Kernel E: final MLP ----------------
__global__ void mlp_out(const float* __restrict__ hcat,
                        const float* __restrict__ W1, const float* __restrict__ b1,
                        const float* __restrict__ W2, const float* __restrict__ b2,
                        float* __restrict__ out) {
  __shared__ float hrow[2 * HH];
  __shared__ float ybuf[NL];
  int bt = blockIdx.x;
  int tid = threadIdx.x;  // 64
  for (int idx = tid; idx < 2 * HH; idx += 64) hrow[idx] = hcat[(size_t)bt * 2 * HH + idx];
  __syncthreads();
  if (tid < NL) {
    const float* wr = W1 + (size_t)tid * 2 * HH;
    float acc = b1[tid];
#pragma unroll 4
    for (int i = 0; i < 2 * HH; i++) acc += wr[i] * hrow[i];
    ybuf[tid] = fmaxf(acc, 0.f);
  }
  __syncthreads();
  if (tid < OD) {
    const float* wr = W2 + (size_t)tid * NL;
    float acc = b2[tid];
#pragma unroll 2
    for (int j = 0; j < NL; j++) acc += wr[j] * ybuf[j];
    out[(size_t)bt * OD + tid] = acc;
  }
}

extern "C" void kernel_launch(void* const* d_in, const int* in_sizes, int n_in,
                              void* d_out, int out_size, void* d_ws, size_t ws_size,
                              hipStream_t stream) {
  const float* x          = (const float*)d_in[0];
  const float* time_steps = (const float*)d_in[1];
  const float* query      = (const float*)d_in[2];
  const float* e1_wp = (const float*)d_in[3];
  const float* e1_bp = (const float*)d_in[4];
  const float* e1_wl = (const float*)d_in[5];
  const float* e1_bl = (const float*)d_in[6];
  const float* e2_wp = (const float*)d_in[7];
  const float* e2_bp = (const float*)d_in[8];
  const float* e2_wl = (const float*)d_in[9];
  const float* e2_bl = (const float*)d_in[10];
  const float* Wq = (const float*)d_in[11];
  const float* bq = (const float*)d_in[12];
  const float* Wk = (const float*)d_in[13];
  const float* bk = (const float*)d_in[14];
  const float* Wo = (const float*)d_in[15];
  const float* bo = (const float*)d_in[16];
  const float* gwi_f = (const float*)d_in[17];
  const float* gwh_f = (const float*)d_in[18];
  const float* gbi_f = (const float*)d_in[19];
  const float* gbh_f = (const float*)d_in[20];
  const float* gwi_b = (const float*)d_in[21];
  const float* gwh_b = (const float*)d_in[22];
  const float* gbi_b = (const float*)d_in[23];
  const float* gbh_b = (const float*)d_in[24];
  const float* W1 = (const float*)d_in[25];
  const float* b1 = (const float*)d_in[26];
  const float* W2 = (const float*)d_in[27];
  const float* b2 = (const float*)d_in[28];

  float* ws    = (float*)d_ws;
  float* kproj = ws;                       // 4096*128
  float* qproj = kproj + 4096 * 128;       // 128*128
  float* xs    = qproj + 128 * 128;        // 128*8*128
  float* gi    = xs + 128 * 8 * 128;       // 2*128*8*384
  float* hcat  = gi + 2 * 128 * 8 * 384;   // 8*128*256

  embed_project<<<4224, 128, 0, stream>>>(time_steps, query,
                                          e1_wp, e1_bp, e1_wl, e1_bl,
                                          e2_wp, e2_bp, e2_wl, e2_bl,
                                          Wk, bk, Wq, bq, kproj, qproj);
  attention<<<1024, 256, 0, stream>>>(x, kproj, qproj, Wo, bo, xs);
  gi_precompute<<<256, 384, 0, stream>>>(xs, gwi_f, gbi_f, gwi_b, gbi_b, gi);
  gru_seq<<<2, 512, 0, stream>>>(gi, gwh_f, gbh_f, gwh_b, gbh_b, hcat);
  mlp_out<<<1024, 64, 0, stream>>>(hcat, W1, b1, W2, b2, (float*)d_out);
}

// Round 6
// 183.670 us; speedup vs baseline: 1.6386x; 1.6370x over previous
//
#include <hip/hip_runtime.h>
#include <math.h>

#define TKK 512
#define TQQ 128
#define BB  8
#define EE  128
#define DD  82
#define IND 41
#define HH  128
#define G3  384
#define NL  50
#define OD  40

typedef __attribute__((ext_vector_type(8))) short short8v;
typedef __attribute__((ext_vector_type(4))) float f32x4;
#define MFMA16(a, b, c) __builtin_amdgcn_mfma_f32_16x16x32_bf16(a, b, c, 0, 0, 0)

__device__ __forceinline__ short f2bf(float f) {
  unsigned u = __float_as_uint(f);
  unsigned r = (u + 0x7fffu + ((u >> 16) & 1u)) >> 16;  // RNE
  return (short)r;
}

// ---------------- Kernel A: time embeddings + K/Q projections ----------------
__global__ void embed_project(const float* __restrict__ time_steps,
                              const float* __restrict__ query,
                              const float* __restrict__ e1_wp, const float* __restrict__ e1_bp,
                              const float* __restrict__ e1_wl, const float* __restrict__ e1_bl,
                              const float* __restrict__ e2_wp, const float* __restrict__ e2_bp,
                              const float* __restrict__ e2_wl, const float* __restrict__ e2_bl,
                              const float* __restrict__ Wk, const float* __restrict__ bk,
                              const float* __restrict__ Wq, const float* __restrict__ bq,
                              float* __restrict__ kproj, float* __restrict__ qproj) {
  __shared__ float emb[EE];
  int row = blockIdx.x;
  int e = threadIdx.x;
  float t; const float *wp, *bp, *wl, *bl, *W, *bias; float* out;
  if (row < BB * TKK) {
    t = time_steps[row];
    wp = e1_wp; bp = e1_bp; wl = e1_wl; bl = e1_bl; W = Wk; bias = bk;
    out = kproj + (size_t)row * EE;
  } else {
    int qi = row - BB * TKK;
    t = query[qi];
    wp = e2_wp; bp = e2_bp; wl = e2_wl; bl = e2_bl; W = Wq; bias = bq;
    out = qproj + (size_t)qi * EE;
  }
  emb[e] = (e == 0) ? (t * wl[0] + bl[0]) : sinf(t * wp[e - 1] + bp[e - 1]);
  __syncthreads();
  const float4* wr = (const float4*)(W + (size_t)e * EE);
  const float4* ev = (const float4*)emb;
  float acc = bias[e];
#pragma unroll 8
  for (int i = 0; i < EE / 4; i++) {
    float4 a = wr[i]; float4 c = ev[i];
    acc += a.x * c.x + a.y * c.y + a.z * c.z + a.w * c.w;
  }
  out[e] = acc;
}

// ---------------- Kernel B: masked-softmax attention + Wo projection ----------------
__global__ void attention(const float* __restrict__ x,
                          const float* __restrict__ kproj,
                          const float* __restrict__ qproj,
                          const float* __restrict__ Wo, const float* __restrict__ bo,
                          float* __restrict__ xs) {
  __shared__ float qv[EE];
  __shared__ float w[TKK];
  __shared__ float red[8];
  __shared__ float part[2 * DD];
  __shared__ float numb[DD];
  __shared__ float attb[DD];
  int b = blockIdx.x >> 7, q = blockIdx.x & 127;
  int tid = threadIdx.x;  // 256
  if (tid < EE) qv[tid] = qproj[(size_t)q * EE + tid];
  __syncthreads();
  float lmax = -1e30f;
  for (int r = 0; r < 2; r++) {
    int k = tid + r * 256;
    const float4* kr = (const float4*)(kproj + (size_t)(b * TKK + k) * EE);
    const float4* qv4 = (const float4*)qv;
    float acc = 0.f;
#pragma unroll 8
    for (int i = 0; i < EE / 4; i++) {
      float4 a = kr[i]; float4 c = qv4[i];
      acc += a.x * c.x + a.y * c.y + a.z * c.z + a.w * c.w;
    }
    acc *= 0.08838834764831845f;  // 1/sqrt(128)
    w[k] = acc;
    lmax = fmaxf(lmax, acc);
  }
  for (int off = 32; off; off >>= 1) lmax = fmaxf(lmax, __shfl_xor(lmax, off, 64));
  if ((tid & 63) == 0) red[tid >> 6] = lmax;
  __syncthreads();
  if (tid == 0) {
    float m = red[0];
    for (int i = 1; i < 4; i++) m = fmaxf(m, red[i]);
    red[0] = m;
  }
  __syncthreads();
  float m = red[0];
  for (int r = 0; r < 2; r++) { int k = tid + r * 256; w[k] = __expf(w[k] - m); }
  __syncthreads();
  if (tid < 2 * DD) {
    int c = tid / DD, d = tid - c * DD;
    const float* xp = x + (size_t)(b * TKK + c * 256) * DD + d;
    float acc = 0.f;
#pragma unroll 4
    for (int k = 0; k < 256; k++) acc += w[c * 256 + k] * xp[(size_t)k * DD];
    part[tid] = acc;
  }
  __syncthreads();
  if (tid < DD) numb[tid] = part[tid] + part[DD + tid];
  __syncthreads();
  if (tid < DD) {
    int j = tid % IND;
    attb[tid] = numb[tid] / numb[IND + j];
  }
  __syncthreads();
  if (tid < HH) {
    const float* wo = Wo + (size_t)tid * DD;
    float acc = bo[tid];
#pragma unroll 2
    for (int d = 0; d < DD; d++) acc += wo[d] * attb[d];
    xs[((size_t)q * BB + b) * HH + tid] = acc;  // xs layout [TQ][B][H]
  }
}

// ---------------- Kernel C: precompute input gates gi ----------------
__global__ void gi_precompute(const float* __restrict__ xs,
                              const float* __restrict__ gwi_f, const float* __restrict__ gbi_f,
                              const float* __restrict__ gwi_b, const float* __restrict__ gbi_b,
                              float* __restrict__ gi) {
  __shared__ float xr[BB][EE];
  int dir = blockIdx.x >> 7, t = blockIdx.x & 127;
  const float* Wi = dir ? gwi_b : gwi_f;
  const float* bi = dir ? gbi_b : gbi_f;
  int tid = threadIdx.x;  // 384
  for (int idx = tid; idx < BB * EE; idx += G3)
    xr[idx >> 7][idx & 127] = xs[(size_t)t * BB * EE + idx];
  __syncthreads();
  const float* wr = Wi + (size_t)tid * EE;
  float bias = bi[tid];
  float acc[BB];
#pragma unroll
  for (int b = 0; b < BB; b++) acc[b] = bias;
  for (int i = 0; i < EE; i++) {
    float wv = wr[i];
#pragma unroll
    for (int b = 0; b < BB; b++) acc[b] += wv * xr[b][i];
  }
  size_t base = ((size_t)(dir * TQQ + t) * BB) * G3 + tid;
#pragma unroll
  for (int b = 0; b < BB; b++) gi[base + (size_t)b * G3] = acc[b];
}

// ---------------- Kernel D: sequential GRU via MFMA, dir×batch split ----------------
// 16 blocks = (dir, b) on 16 CUs, 512 threads = 8 waves each.
// M=1 trick: all four 16-lane groups read the SAME h address (broadcast), so
// every C row duplicates the true row and reg 0 of EVERY lane is valid.
// Wave w owns h-cols 16w..16w+15 for all 3 gates (12 MFMAs/wave/step).
// Tail: 16 lanes/wave (lhi==0) do the pointwise GRU for their own columns.
// h double-buffered as 128 bf16 in LDS; raw barrier (no vmcnt drain).
__global__ __launch_bounds__(512, 1) void gru_seq(const float* __restrict__ gi,
                                                  const float* __restrict__ gwh_f,
                                                  const float* __restrict__ gbh_f,
                                                  const float* __restrict__ gwh_b,
                                                  const float* __restrict__ gbh_b,
                                                  float* __restrict__ hcat) {
  __shared__ short hb[2][HH];  // 2 x 128 bf16 = 512 B
  int dir = blockIdx.x >> 3, b = blockIdx.x & 7;
  const float* Wh = dir ? gwh_b : gwh_f;
  const float* bh = dir ? gbh_b : gbh_f;
  int tid = threadIdx.x;
  int w = tid >> 6, l = tid & 63;
  int lhi = l >> 4, llo = l & 15;
  int o = 16 * w + llo;      // h-column this lane covers (duplicated across lhi)
  bool tl = (lhi == 0);      // tail lanes: one per distinct column

  for (int i = tid; i < 2 * HH / 2; i += 512) ((int*)hb)[i] = 0;

  // B fragments: B[k][n] = Wh[gate*128 + o][k], lane supplies k = kk*32+lhi*8+[0..8)
  short8v Bf[3][4];
#pragma unroll
  for (int g = 0; g < 3; g++) {
    const float* wr = Wh + (size_t)(g * HH + o) * EE;
#pragma unroll
    for (int kk = 0; kk < 4; kk++) {
      int k0 = kk * 32 + lhi * 8;
      short8v v;
#pragma unroll
      for (int i = 0; i < 8; i++) v[i] = f2bf(wr[k0 + i]);
      Bf[g][kk] = v;
    }
  }
  float bhr = bh[o], bhz = bh[HH + o], bhn = bh[2 * HH + o];
  float hprev = 0.f;

  // gi rotating buffers (static indices), [r,z,n]
  float g0[3], g1[3], g2[3], g3[3];
  const size_t dbase = (size_t)dir * TQQ * BB * G3 + (size_t)b * G3 + o;

  auto gi_load = [&](int step, float (&dst)[3]) {
    int tt = dir ? (TQQ - 1 - step) : step;
    const float* gp = gi + dbase + (size_t)tt * (BB * G3);
    dst[0] = gp[0]; dst[1] = gp[HH]; dst[2] = gp[2 * HH];
  };
  __syncthreads();  // h buffers visible
  gi_load(0, g0); gi_load(1, g1);

  auto body = [&](int step, float (&gc)[3], float (&gn)[3]) {
    int cur = step & 1;
    // A fragments: all 16-lane groups read the same 16 B (broadcast): the k
    // slice for group lhi is h[kk*32 + lhi*8 .. +8) -> byte kk*64 + lhi*16.
    const char* hrow = (const char*)&hb[cur][0];
    short8v A0 = *(const short8v*)(hrow + 0 * 64 + lhi * 16);
    short8v A1 = *(const short8v*)(hrow + 1 * 64 + lhi * 16);
    short8v A2 = *(const short8v*)(hrow + 2 * 64 + lhi * 16);
    short8v A3 = *(const short8v*)(hrow + 3 * 64 + lhi * 16);
    // prefetch gi two steps ahead (stays in flight across raw barriers)
    { int ls = step + 2; gi_load(ls > TQQ - 1 ? TQQ - 1 : ls, gn); }
    f32x4 z4 = {0.f, 0.f, 0.f, 0.f};
    f32x4 aR = z4, aZ = z4, aN = z4;
    aR = MFMA16(A0, Bf[0][0], aR); aZ = MFMA16(A0, Bf[1][0], aZ); aN = MFMA16(A0, Bf[2][0], aN);
    aR = MFMA16(A1, Bf[0][1], aR); aZ = MFMA16(A1, Bf[1][1], aZ); aN = MFMA16(A1, Bf[2][1], aN);
    aR = MFMA16(A2, Bf[0][2], aR); aZ = MFMA16(A2, Bf[1][2], aZ); aN = MFMA16(A2, Bf[2][2], aN);
    aR = MFMA16(A3, Bf[0][3], aR); aZ = MFMA16(A3, Bf[1][3], aZ); aN = MFMA16(A3, Bf[2][3], aN);
    if (tl) {
      int t = dir ? (TQQ - 1 - step) : step;
      float rp = gc[0] + bhr + aR[0];
      float zp = gc[1] + bhz + aZ[0];
      float hn = aN[0] + bhn;
      float r = 1.f / (1.f + __expf(-rp));
      float z = 1.f / (1.f + __expf(-zp));
      float a = gc[2] + r * hn;
      float e = __expf(2.f * a);
      float n = 1.f - 2.f / (1.f + e);  // tanh(a), saturation-safe
      float hnew = n + z * (hprev - n);
      hprev = hnew;
      hb[cur ^ 1][o] = f2bf(hnew);
      hcat[((size_t)b * TQQ + t) * (2 * HH) + dir * HH + o] = hnew;
    }
    // LDS-only sync: drain own ds ops, raw barrier, no vmcnt(0) drain
    asm volatile("s_waitcnt lgkmcnt(0)" ::: "memory");
    __builtin_amdgcn_s_barrier();
    __builtin_amdgcn_sched_barrier(0);
  };

  for (int so = 0; so < TQQ / 4; so++) {
    body(so * 4 + 0, g0, g2);
    body(so * 4 + 1, g1, g3);
    body(so * 4 + 2, g2, g0);
    body(so * 4 + 3, g3, g1);
  }
}

// ---------------- Kernel E: final MLP ----------------
__global__ void mlp_out(const float* __restrict__ hcat,
                        const float* __restrict__ W1, const float* __restrict__ b1,
                        const float* __restrict__ W2, const float* __restrict__ b2,
                        float* __restrict__ out) {
  __shared__ float hrow[2 * HH];
  __shared__ float ybuf[NL];
  int bt = blockIdx.x;
  int tid = threadIdx.x;  // 64
  for (int idx = tid; idx < 2 * HH; idx += 64) hrow[idx] = hcat[(size_t)bt * 2 * HH + idx];
  __syncthreads();
  if (tid < NL) {
    const float* wr = W1 + (size_t)tid * 2 * HH;
    float acc = b1[tid];
#pragma unroll 4
    for (int i = 0; i < 2 * HH; i++) acc += wr[i] * hrow[i];
    ybuf[tid] = fmaxf(acc, 0.f);
  }
  __syncthreads();
  if (tid < OD) {
    const float* wr = W2 + (size_t)tid * NL;
    float acc = b2[tid];
#pragma unroll 2
    for (int j = 0; j < NL; j++) acc += wr[j] * ybuf[j];
    out[(size_t)bt * OD + tid] = acc;
  }
}

extern "C" void kernel_launch(void* const* d_in, const int* in_sizes, int n_in,
                              void* d_out, int out_size, void* d_ws, size_t ws_size,
                              hipStream_t stream) {
  const float* x          = (const float*)d_in[0];
  const float* time_steps = (const float*)d_in[1];
  const float* query      = (const float*)d_in[2];
  const float* e1_wp = (const float*)d_in[3];
  const float* e1_bp = (const float*)d_in[4];
  const float* e1_wl = (const float*)d_in[5];
  const float* e1_bl = (const float*)d_in[6];
  const float* e2_wp = (const float*)d_in[7];
  const float* e2_bp = (const float*)d_in[8];
  const float* e2_wl = (const float*)d_in[9];
  const float* e2_bl = (const float*)d_in[10];
  const float* Wq = (const float*)d_in[11];
  const float* bq = (const float*)d_in[12];
  const float* Wk = (const float*)d_in[13];
  const float* bk = (const float*)d_in[14];
  const float* Wo = (const float*)d_in[15];
  const float* bo = (const float*)d_in[16];
  const float* gwi_f = (const float*)d_in[17];
  const float* gwh_f = (const float*)d_in[18];
  const float* gbi_f = (const float*)d_in[19];
  const float* gbh_f = (const float*)d_in[20];
  const float* gwi_b = (const float*)d_in[21];
  const float* gwh_b = (const float*)d_in[22];
  const float* gbi_b = (const float*)d_in[23];
  const float* gbh_b = (const float*)d_in[24];
  const float* W1 = (const float*)d_in[25];
  const float* b1 = (const float*)d_in[26];
  const float* W2 = (const float*)d_in[27];
  const float* b2 = (const float*)d_in[28];

  float* ws    = (float*)d_ws;
  float* kproj = ws;                       // 4096*128
  float* qproj = kproj + 4096 * 128;       // 128*128
  float* xs    = qproj + 128 * 128;        // 128*8*128
  float* gi    = xs + 128 * 8 * 128;       // 2*128*8*384
  float* hcat  = gi + 2 * 128 * 8 * 384;   // 8*128*256

  embed_project<<<4224, 128, 0, stream>>>(time_steps, query,
                                          e1_wp, e1_bp, e1_wl, e1_bl,
                                          e2_wp, e2_bp, e2_wl, e2_bl,
                                          Wk, bk, Wq, bq, kproj, qproj);
  attention<<<1024, 256, 0, stream>>>(x, kproj, qproj, Wo, bo, xs);
  gi_precompute<<<256, 384, 0, stream>>>(xs, gwi_f, gbi_f, gwi_b, gbi_b, gi);
  gru_seq<<<16, 512, 0, stream>>>(gi, gwh_f, gbh_f, gwh_b, gbh_b, hcat);
  mlp_out<<<1024, 64, 0, stream>>>(hcat, W1, b1, W2, b2, (float*)d_out);
}

// Round 7
// 123.989 us; speedup vs baseline: 2.4274x; 1.4813x over previous
//
#include <hip/hip_runtime.h>
#include <math.h>

#define TKK 512
#define TQQ 128
#define BB  8
#define EE  128
#define DD  82
#define IND 41
#define HH  128
#define G3  384
#define NL  50
#define OD  40

typedef __attribute__((ext_vector_type(8))) short short8v;
typedef __attribute__((ext_vector_type(4))) float f32x4;
#define MFMA16(a, b, c) __builtin_amdgcn_mfma_f32_16x16x32_bf16(a, b, c, 0, 0, 0)

__device__ __forceinline__ short f2bf(float f) {
  unsigned u = __float_as_uint(f);
  unsigned r = (u + 0x7fffu + ((u >> 16) & 1u)) >> 16;  // RNE
  return (short)r;
}
__device__ __forceinline__ float dot4(float4 a, float4 b) {
  return a.x * b.x + a.y * b.y + a.z * b.z + a.w * b.w;
}

// ---------------- Kernel A: time embeddings + K/Q projections ----------------
// 8 rows per block. Blocks [0,512): kproj, b = i&7 (XCD-local to consumer).
// Blocks [512,528): qproj.
__global__ __launch_bounds__(128) void embed_project(
    const float* __restrict__ time_steps, const float* __restrict__ query,
    const float* __restrict__ e1_wp, const float* __restrict__ e1_bp,
    const float* __restrict__ e1_wl, const float* __restrict__ e1_bl,
    const float* __restrict__ e2_wp, const float* __restrict__ e2_bp,
    const float* __restrict__ e2_wl, const float* __restrict__ e2_bl,
    const float* __restrict__ Wk, const float* __restrict__ bk,
    const float* __restrict__ Wq, const float* __restrict__ bq,
    float* __restrict__ kproj, float* __restrict__ qproj) {
  __shared__ float emb[8][EE];
  int i = blockIdx.x;
  int e = threadIdx.x;
  const float *wp, *bp, *wl, *bl, *W, *bias;
  float* out;
  int row0;
  const float* tsrc;
  if (i < 512) {
    int b = i & 7, rg = i >> 3;
    row0 = b * TKK + rg * 8;
    tsrc = time_steps + row0;
    wp = e1_wp; bp = e1_bp; wl = e1_wl; bl = e1_bl; W = Wk; bias = bk;
    out = kproj + (size_t)row0 * EE;
  } else {
    int qg = i - 512;
    row0 = qg * 8;
    tsrc = query + row0;
    wp = e2_wp; bp = e2_bp; wl = e2_wl; bl = e2_bl; W = Wq; bias = bq;
    out = qproj + (size_t)row0 * EE;
  }
  float wpv = 0.f, bpv = 0.f;
  if (e > 0) { wpv = wp[e - 1]; bpv = bp[e - 1]; }
  float wlv = wl[0], blv = bl[0];
#pragma unroll
  for (int r = 0; r < 8; r++) {
    float t = tsrc[r];
    emb[r][e] = (e == 0) ? (t * wlv + blv) : sinf(t * wpv + bpv);
  }
  __syncthreads();
  const float4* wr4 = (const float4*)(W + (size_t)e * EE);
  const float4* em4 = (const float4*)emb;
  float bv = bias[e];
  float acc[8];
#pragma unroll
  for (int r = 0; r < 8; r++) acc[r] = bv;
#pragma unroll 4
  for (int c = 0; c < 32; c++) {
    float4 wv = wr4[c];
#pragma unroll
    for (int r = 0; r < 8; r++) acc[r] += dot4(wv, em4[r * 32 + c]);
  }
#pragma unroll
  for (int r = 0; r < 8; r++) out[(size_t)r * EE + e] = acc[r];
}

// ---------------- Kernel B: attention + Wo + gi (fused) ----------------
// 256 blocks: b = bid&7 (XCD-local), qg = bid>>3, q = 4*qg..+4. 256 threads.
__global__ __launch_bounds__(256) void attention(
    const float* __restrict__ x, const float* __restrict__ kproj,
    const float* __restrict__ qproj, const float* __restrict__ Wo,
    const float* __restrict__ bo,
    const float* __restrict__ gwi_f, const float* __restrict__ gbi_f,
    const float* __restrict__ gwi_b, const float* __restrict__ gbi_b,
    float* __restrict__ gi) {
  __shared__ float qv[4][EE];
  __shared__ float4 w4[TKK];
  __shared__ float red[4][4];
  __shared__ float mfin[4];
  __shared__ float part[2][4][DD];
  __shared__ float numb[4][DD];
  __shared__ float attb[4][DD];
  __shared__ float xsr[4][EE];
  int b = blockIdx.x & 7, qg = blockIdx.x >> 3;
  int q0 = qg * 4;
  int tid = threadIdx.x;

  // stage 4 qproj rows
  {
    int idx = tid * 2, qi = idx >> 7, j = idx & 127;
    *(float2*)&qv[qi][j] = *(const float2*)(qproj + (size_t)(q0 + qi) * EE + j);
  }
  __syncthreads();

  // scores: thread owns k rows tid and tid+256, 4 q's each
  float s0[4] = {0.f, 0.f, 0.f, 0.f}, s1[4] = {0.f, 0.f, 0.f, 0.f};
  {
    const float4* kr0 = (const float4*)(kproj + (size_t)(b * TKK + tid) * EE);
    const float4* kr1 = (const float4*)(kproj + (size_t)(b * TKK + 256 + tid) * EE);
    const float4* qv4 = (const float4*)qv;
#pragma unroll 8
    for (int c = 0; c < 32; c++) {
      float4 a0 = kr0[c], a1 = kr1[c];
#pragma unroll
      for (int qi = 0; qi < 4; qi++) {
        float4 cv = qv4[qi * 32 + c];
        s0[qi] += dot4(a0, cv);
        s1[qi] += dot4(a1, cv);
      }
    }
  }
  const float scale = 0.08838834764831845f;  // 1/sqrt(128)
  float lm[4];
#pragma unroll
  for (int qi = 0; qi < 4; qi++) {
    s0[qi] *= scale; s1[qi] *= scale;
    lm[qi] = fmaxf(s0[qi], s1[qi]);
  }
  for (int off = 32; off; off >>= 1)
#pragma unroll
    for (int qi = 0; qi < 4; qi++) lm[qi] = fmaxf(lm[qi], __shfl_xor(lm[qi], off, 64));
  if ((tid & 63) == 0)
#pragma unroll
    for (int qi = 0; qi < 4; qi++) red[tid >> 6][qi] = lm[qi];
  __syncthreads();
  if (tid < 4) {
    float m = red[0][tid];
    for (int w = 1; w < 4; w++) m = fmaxf(m, red[w][tid]);
    mfin[tid] = m;
  }
  __syncthreads();
  {
    float m0 = mfin[0], m1 = mfin[1], m2 = mfin[2], m3 = mfin[3];
    float4 e0, e1;
    e0.x = __expf(s0[0] - m0); e0.y = __expf(s0[1] - m1);
    e0.z = __expf(s0[2] - m2); e0.w = __expf(s0[3] - m3);
    e1.x = __expf(s1[0] - m0); e1.y = __expf(s1[1] - m1);
    e1.z = __expf(s1[2] - m2); e1.w = __expf(s1[3] - m3);
    w4[tid] = e0; w4[256 + tid] = e1;
  }
  __syncthreads();

  // weighted numerators: thread (c,d) accumulates 4 q's over 256 k
  if (tid < 2 * DD) {
    int c = (tid >= DD), d = tid - c * DD;
    const float* xp = x + ((size_t)(b * TKK + c * 256)) * DD + d;
    float a0 = 0.f, a1 = 0.f, a2 = 0.f, a3 = 0.f;
#pragma unroll 8
    for (int k = 0; k < 256; k++) {
      float xv = xp[(size_t)k * DD];
      float4 wv = w4[c * 256 + k];
      a0 += wv.x * xv; a1 += wv.y * xv; a2 += wv.z * xv; a3 += wv.w * xv;
    }
    part[c][0][d] = a0; part[c][1][d] = a1; part[c][2][d] = a2; part[c][3][d] = a3;
  }
  __syncthreads();
  if (tid < DD) {
#pragma unroll
    for (int qi = 0; qi < 4; qi++) numb[qi][tid] = part[0][qi][tid] + part[1][qi][tid];
  }
  __syncthreads();
  if (tid < DD) {
    int j = tid % IND;
#pragma unroll
    for (int qi = 0; qi < 4; qi++) attb[qi][tid] = numb[qi][tid] / numb[qi][IND + j];
  }
  __syncthreads();

  // Wo projection -> xsr[4][128]
  {
    int o = tid & 127, g = tid >> 7;  // g in {0,1}, handles q = 2g, 2g+1
    const float* wo = Wo + (size_t)o * DD;
    float acc0 = bo[o], acc1 = acc0;
#pragma unroll 2
    for (int d = 0; d < DD; d++) {
      float wv = wo[d];
      acc0 += wv * attb[2 * g][d];
      acc1 += wv * attb[2 * g + 1][d];
    }
    xsr[2 * g][o] = acc0;
    xsr[2 * g + 1][o] = acc1;
  }
  __syncthreads();

  // gi: 768 gate-cols x 4 q. gi layout [dir*8+b][t][384].
  const float4* xs4 = (const float4*)xsr;
#pragma unroll
  for (int kk = 0; kk < 3; kk++) {
    int o = tid + kk * 256;
    int dirn = (o >= G3) ? 1 : 0;
    int oo = o - dirn * G3;
    const float4* wr = (const float4*)((dirn ? gwi_b : gwi_f) + (size_t)oo * EE);
    float bi = (dirn ? gbi_b : gbi_f)[oo];
    float a0 = bi, a1 = bi, a2 = bi, a3 = bi;
#pragma unroll 4
    for (int c = 0; c < 32; c++) {
      float4 wv = wr[c];
      a0 += dot4(wv, xs4[0 * 32 + c]);
      a1 += dot4(wv, xs4[1 * 32 + c]);
      a2 += dot4(wv, xs4[2 * 32 + c]);
      a3 += dot4(wv, xs4[3 * 32 + c]);
    }
    size_t gbase = ((size_t)(dirn * BB + b) * TQQ + q0) * G3 + oo;
    gi[gbase] = a0; gi[gbase + G3] = a1; gi[gbase + 2 * G3] = a2; gi[gbase + 3 * G3] = a3;
  }
}

// ---------------- Kernel D: sequential GRU via MFMA, dir×batch split ----------------
// 16 blocks = (dir, b), b = wgid&7 -> XCD b (same XCD that produced gi[.][b]).
__global__ __launch_bounds__(512, 1) void gru_seq(const float* __restrict__ gi,
                                                  const float* __restrict__ gwh_f,
                                                  const float* __restrict__ gbh_f,
                                                  const float* __restrict__ gwh_b,
                                                  const float* __restrict__ gbh_b,
                                                  float* __restrict__ hcat) {
  __shared__ short hb[2][HH];  // 2 x 128 bf16
  int dir = blockIdx.x >> 3, b = blockIdx.x & 7;
  const float* Wh = dir ? gwh_b : gwh_f;
  const float* bh = dir ? gbh_b : gbh_f;
  int tid = threadIdx.x;
  int w = tid >> 6, l = tid & 63;
  int lhi = l >> 4, llo = l & 15;
  int o = 16 * w + llo;
  bool tl = (lhi == 0);

  for (int i = tid; i < 2 * HH / 2; i += 512) ((int*)hb)[i] = 0;

  short8v Bf[3][4];
#pragma unroll
  for (int g = 0; g < 3; g++) {
    const float* wr = Wh + (size_t)(g * HH + o) * EE;
#pragma unroll
    for (int kk = 0; kk < 4; kk++) {
      int k0 = kk * 32 + lhi * 8;
      short8v v;
#pragma unroll
      for (int i = 0; i < 8; i++) v[i] = f2bf(wr[k0 + i]);
      Bf[g][kk] = v;
    }
  }
  float bhr = bh[o], bhz = bh[HH + o], bhn = bh[2 * HH + o];
  float hprev = 0.f;

  float g0[3], g1[3], g2[3], g3[3];
  const size_t dbase = ((size_t)(dir * BB + b) * TQQ) * G3 + o;

  auto gi_load = [&](int step, float (&dst)[3]) {
    int tt = dir ? (TQQ - 1 - step) : step;
    const float* gp = gi + dbase + (size_t)tt * G3;
    dst[0] = gp[0]; dst[1] = gp[HH]; dst[2] = gp[2 * HH];
  };
  __syncthreads();
  gi_load(0, g0); gi_load(1, g1);

  auto body = [&](int step, float (&gc)[3], float (&gn)[3]) {
    int cur = step & 1;
    const char* hrow = (const char*)&hb[cur][0];
    short8v A0 = *(const short8v*)(hrow + 0 * 64 + lhi * 16);
    short8v A1 = *(const short8v*)(hrow + 1 * 64 + lhi * 16);
    short8v A2 = *(const short8v*)(hrow + 2 * 64 + lhi * 16);
    short8v A3 = *(const short8v*)(hrow + 3 * 64 + lhi * 16);
    { int ls = step + 2; gi_load(ls > TQQ - 1 ? TQQ - 1 : ls, gn); }
    f32x4 z4 = {0.f, 0.f, 0.f, 0.f};
    f32x4 aR = z4, aZ = z4, aN = z4;
    aR = MFMA16(A0, Bf[0][0], aR); aZ = MFMA16(A0, Bf[1][0], aZ); aN = MFMA16(A0, Bf[2][0], aN);
    aR = MFMA16(A1, Bf[0][1], aR); aZ = MFMA16(A1, Bf[1][1], aZ); aN = MFMA16(A1, Bf[2][1], aN);
    aR = MFMA16(A2, Bf[0][2], aR); aZ = MFMA16(A2, Bf[1][2], aZ); aN = MFMA16(A2, Bf[2][2], aN);
    aR = MFMA16(A3, Bf[0][3], aR); aZ = MFMA16(A3, Bf[1][3], aZ); aN = MFMA16(A3, Bf[2][3], aN);
    if (tl) {
      int t = dir ? (TQQ - 1 - step) : step;
      float rp = gc[0] + bhr + aR[0];
      float zp = gc[1] + bhz + aZ[0];
      float hn = aN[0] + bhn;
      float r = 1.f / (1.f + __expf(-rp));
      float z = 1.f / (1.f + __expf(-zp));
      float a = gc[2] + r * hn;
      float e = __expf(2.f * a);
      float n = 1.f - 2.f / (1.f + e);
      float hnew = n + z * (hprev - n);
      hprev = hnew;
      hb[cur ^ 1][o] = f2bf(hnew);
      hcat[((size_t)b * TQQ + t) * (2 * HH) + dir * HH + o] = hnew;
    }
    asm volatile("s_waitcnt lgkmcnt(0)" ::: "memory");
    __builtin_amdgcn_s_barrier();
    __builtin_amdgcn_sched_barrier(0);
  };

  for (int so = 0; so < TQQ / 4; so++) {
    body(so * 4 + 0, g0, g2);
    body(so * 4 + 1, g1, g3);
    body(so * 4 + 2, g2, g0);
    body(so * 4 + 3, g3, g1);
  }
}

// ---------------- Kernel E: final MLP, 8 rows/block ----------------
__global__ __launch_bounds__(512) void mlp_out(const float* __restrict__ hcat,
                                               const float* __restrict__ W1,
                                               const float* __restrict__ b1,
                                               const float* __restrict__ W2,
                                               const float* __restrict__ b2,
                                               float* __restrict__ out) {
  __shared__ float hrow[8][2 * HH];
  __shared__ float ybuf[8][52];
  int i = blockIdx.x;
  int b = i & 7, tg = i >> 3;  // rows bt = b*128 + tg*8 + r  (XCD b = hcat producer)
  int tid = threadIdx.x;
  size_t rowbase = (size_t)(b * TQQ + tg * 8) * (2 * HH);
  ((float4*)hrow)[tid] = *(const float4*)(hcat + rowbase + tid * 4);
  __syncthreads();
  int r = tid >> 6, o = tid & 63;
  if (o < NL) {
    const float4* w1 = (const float4*)(W1 + (size_t)o * (2 * HH));
    const float4* h4 = (const float4*)hrow[r];
    float acc = b1[o];
#pragma unroll 8
    for (int c = 0; c < 64; c++) acc += dot4(w1[c], h4[c]);
    ybuf[r][o] = fmaxf(acc, 0.f);
  }
  __syncthreads();
  if (o < OD) {
    const float* w2 = W2 + (size_t)o * NL;
    float acc = b2[o];
#pragma unroll 10
    for (int j = 0; j < NL; j++) acc += w2[j] * ybuf[r][j];
    out[((size_t)(b * TQQ + tg * 8) + r) * OD + o] = acc;
  }
}

extern "C" void kernel_launch(void* const* d_in, const int* in_sizes, int n_in,
                              void* d_out, int out_size, void* d_ws, size_t ws_size,
                              hipStream_t stream) {
  const float* x          = (const float*)d_in[0];
  const float* time_steps = (const float*)d_in[1];
  const float* query      = (const float*)d_in[2];
  const float* e1_wp = (const float*)d_in[3];
  const float* e1_bp = (const float*)d_in[4];
  const float* e1_wl = (const float*)d_in[5];
  const float* e1_bl = (const float*)d_in[6];
  const float* e2_wp = (const float*)d_in[7];
  const float* e2_bp = (const float*)d_in[8];
  const float* e2_wl = (const float*)d_in[9];
  const float* e2_bl = (const float*)d_in[10];
  const float* Wq = (const float*)d_in[11];
  const float* bq = (const float*)d_in[12];
  const float* Wk = (const float*)d_in[13];
  const float* bk = (const float*)d_in[14];
  const float* Wo = (const float*)d_in[15];
  const float* bo = (const float*)d_in[16];
  const float* gwi_f = (const float*)d_in[17];
  const float* gwh_f = (const float*)d_in[18];
  const float* gbi_f = (const float*)d_in[19];
  const float* gbh_f = (const float*)d_in[20];
  const float* gwi_b = (const float*)d_in[21];
  const float* gwh_b = (const float*)d_in[22];
  const float* gbi_b = (const float*)d_in[23];
  const float* gbh_b = (const float*)d_in[24];
  const float* W1 = (const float*)d_in[25];
  const float* b1 = (const float*)d_in[26];
  const float* W2 = (const float*)d_in[27];
  const float* b2 = (const float*)d_in[28];

  float* ws    = (float*)d_ws;
  float* kproj = ws;                        // 4096*128
  float* qproj = kproj + 4096 * 128;        // 128*128
  float* gi    = qproj + 128 * 128;         // [2*8][128][384]
  float* hcat  = gi + 2 * 8 * 128 * 384;    // 8*128*256

  embed_project<<<528, 128, 0, stream>>>(time_steps, query,
                                         e1_wp, e1_bp, e1_wl, e1_bl,
                                         e2_wp, e2_bp, e2_wl, e2_bl,
                                         Wk, bk, Wq, bq, kproj, qproj);
  attention<<<256, 256, 0, stream>>>(x, kproj, qproj, Wo, bo,
                                     gwi_f, gbi_f, gwi_b, gbi_b, gi);
  gru_seq<<<16, 512, 0, stream>>>(gi, gwh_f, gbh_f, gwh_b, gbh_b, hcat);
  mlp_out<<<128, 512, 0, stream>>>(hcat, W1, b1, W2, b2, (float*)d_out);
}